// Round 8
// baseline (370.963 us; speedup 1.0000x reference)
//
#include <hip/hip_runtime.h>
#include <hip/hip_bf16.h>
#include <hip/hip_cooperative_groups.h>
namespace cg = cooperative_groups;

#define N_NODES 100000
#define N_EDGES 3200000
#define F_IN 36
#define F_HID 8
#define F_OUT 2
#define NEG_SLOPE 0.2f

// bucket parameters: 128 nodes per bucket, padded regions of CAP edges
#define GSHIFT 7
#define GNPB 128                     // nodes per bucket
#define GNBUCK 782                   // ceil(N_NODES / GNPB)
#define CAP 4608                     // per-bucket capacity (mean 4092, +8 sigma)
#define NB_PART 256                  // partition blocks (round-5 best config)
#define CHUNK 12500                  // N_EDGES / NB_PART exactly
#define BP 1024                      // block size (partition + node1 sections)
#define NB_NODE1 98                  // ceil(N_NODES / BP)
#define BPG 512                      // fused GAT block size (8 waves)
#define NBLK2 391                    // fused GAT grid: each block owns 2 buckets (2*391=782)

// ---------- inline index-dtype detection (wave 0, 2 loads/lane + ballot) ----------
// int64 input => odd 32-bit words of first 128 index pairs are all zero.
__device__ __forceinline__ int detect_is64(const void* eidx, int* s_flag) {
    if (threadIdx.x < 64) {
        const unsigned int* p = (const unsigned int*)eidx;
        unsigned int v1 = p[2 * threadIdx.x + 1];
        unsigned int v2 = p[2 * (threadIdx.x + 64) + 1];
        unsigned long long m = __ballot(v1 != 0u || v2 != 0u);
        if (threadIdx.x == 0) *s_flag = (m == 0ull) ? 1 : 0;
    }
    __syncthreads();
    return *s_flag;
}

// ---------- merged: partition (blocks 0..255) + node1 transform (blocks 256..353) ----------
__global__ void part_node1_k(const void* __restrict__ eidx, int* __restrict__ gcnt,
                             int* __restrict__ partP,
                             const float* __restrict__ x, const float* __restrict__ W1,
                             const float* __restrict__ aw_d,
                             float* __restrict__ h1, float* __restrict__ ad1) {
    if (blockIdx.x < NB_PART) {
        // ================= partition section =================
        __shared__ int sortbuf[CHUNK];    // 50000 B
        __shared__ int hist[GNBUCK];
        __shared__ int spre[GNBUCK];      // inclusive prefix of hist
        __shared__ int cursor[GNBUCK];
        __shared__ int gbase[GNBUCK];
        __shared__ int s_flag;
        int t = threadIdx.x;
        for (int i = t; i < GNBUCK; i += BP) hist[i] = 0;
        int f = detect_is64(eidx, &s_flag);   // ends with __syncthreads()
        int beg = blockIdx.x * CHUNK;
        int end = beg + CHUNK;                // exact, no partial blocks
        const unsigned int* p32 = (const unsigned int*)eidx;
        // pass 1: histogram of dst buckets (load only the low 4B word of int64)
        if (f) {
            for (int i = beg + t; i < end; i += BP)
                atomicAdd(&hist[(int)p32[2 * (N_EDGES + i)] >> GSHIFT], 1);
        } else {
            const int* p = (const int*)eidx;
            for (int i = beg + t; i < end; i += BP)
                atomicAdd(&hist[p[N_EDGES + i] >> GSHIFT], 1);
        }
        __syncthreads();
        // global reservation + scan init
        if (t < GNBUCK) {
            int c = hist[t];
            gbase[t] = c ? atomicAdd(&gcnt[t], c) : 0;
            spre[t] = c;
        }
        __syncthreads();
        // Hillis-Steele inclusive scan over 782 buckets (10 steps)
        for (int off = 1; off < GNBUCK; off <<= 1) {
            int v = 0;
            if (t < GNBUCK && t >= off) v = spre[t - off];
            __syncthreads();
            if (t < GNBUCK && t >= off) spre[t] += v;
            __syncthreads();
        }
        if (t < GNBUCK) cursor[t] = spre[t] - hist[t];   // exclusive offset
        __syncthreads();
        // pass 2: scatter into LDS sortbuf grouped by bucket (chunk is L2/L3-warm)
        if (f) {
            for (int i = beg + t; i < end; i += BP) {
                int s = (int)p32[2 * i];
                int d = (int)p32[2 * (N_EDGES + i)];
                int b = d >> GSHIFT;
                int pos = atomicAdd(&cursor[b], 1);
                sortbuf[pos] = (s << GSHIFT) | (d & (GNPB - 1));
            }
        } else {
            const int* p = (const int*)eidx;
            for (int i = beg + t; i < end; i += BP) {
                int s = p[i];
                int d = p[N_EDGES + i];
                int b = d >> GSHIFT;
                int pos = atomicAdd(&cursor[b], 1);
                sortbuf[pos] = (s << GSHIFT) | (d & (GNPB - 1));
            }
        }
        __syncthreads();
        // pass 3: coalesced run writes; recover bucket via binary search on spre
        for (int i = t; i < CHUNK; i += BP) {
            int lo = 0, hi = GNBUCK - 1;
            while (lo < hi) {
                int mid = (lo + hi) >> 1;
                if (spre[mid] > i) hi = mid; else lo = mid + 1;
            }
            int b = lo;
            int gp = gbase[b] + (i - (spre[b] - hist[b]));
            if (gp < CAP) partP[b * CAP + gp] = sortbuf[i];
        }
    } else {
        // ================= node1 section: h1 = x @ W1, ad1 ==================
        int n = (blockIdx.x - NB_PART) * BP + threadIdx.x;
        if (n >= N_NODES) return;
        float acc[F_HID];
#pragma unroll
        for (int f = 0; f < F_HID; f++) acc[f] = 0.f;
        const float4* xp = (const float4*)(x + (size_t)n * F_IN);  // 36 floats = 9 float4
#pragma unroll
        for (int q = 0; q < 9; q++) {
            float4 xv = xp[q];
            const float* w = W1 + q * 4 * F_HID;
#pragma unroll
            for (int f = 0; f < F_HID; f++) {
                acc[f] += xv.x * w[0 * F_HID + f] + xv.y * w[1 * F_HID + f]
                        + xv.z * w[2 * F_HID + f] + xv.w * w[3 * F_HID + f];
            }
        }
        float d = 0.f;
#pragma unroll
        for (int f = 0; f < F_HID; f++) d += acc[f] * aw_d[f];
        float4* hp = (float4*)(h1 + (size_t)n * F_HID);
        hp[0] = make_float4(acc[0], acc[1], acc[2], acc[3]);
        hp[1] = make_float4(acc[4], acc[5], acc[6], acc[7]);
        ad1[n] = d;
    }
}

// ---------- fused layers 1+2 (cooperative): each block owns TWO buckets ----------
// Round-8 hardening vs round-7's failed version (zero-output signature => the
// cooperative launch was rejected on co-residency):
//  (1) grid halved to 391 blocks (2 buckets/block, two eL arrays, 40.4KB LDS);
//      __launch_bounds__(512,4) caps VGPR at 128 -> 2 blocks/CU guaranteed ->
//      capacity 512 >= 391 with margin. Launch cannot be occupancy-rejected.
//  (2) P2 written via DEVICE-SCOPE ATOMIC stores (cross-XCD-coherent path;
//      writer-side only, 4x32b per node) + __threadfence on both sides of
//      grid.sync(); phase-2 gathers stay plain float4 loads (first touch).
__global__ __launch_bounds__(BPG, 4)
void gatF12_k(const int* __restrict__ gcnt, const int* __restrict__ partP,
              const float* __restrict__ aw_s1, const float* __restrict__ ad1,
              const float* __restrict__ h1, const float* __restrict__ b1,
              const float* __restrict__ W2, const float* __restrict__ aw_s2,
              const float* __restrict__ aw_d2, float4* __restrict__ P2,
              const float* __restrict__ b2, float* __restrict__ out) {
    __shared__ int eL0[CAP];
    __shared__ int eL1[CAP];
    __shared__ int hist[GNPB];
    __shared__ int nstart[GNPB];
    __shared__ int cursor[GNPB];
    __shared__ int sscan[GNPB];
    __shared__ float adl[GNPB];
    __shared__ float ad2s[2 * GNPB];
    cg::grid_group grid = cg::this_grid();
    int t = threadIdx.x;
    int node = t >> 2;
    int lane = t & 3;

    // a_src1 weights in registers
    float ws0 = aw_s1[0], ws1 = aw_s1[1], ws2 = aw_s1[2], ws3 = aw_s1[3];
    float ws4 = aw_s1[4], ws5 = aw_s1[5], ws6 = aw_s1[6], ws7 = aw_s1[7];

    int ns_r[2], ne_r[2];

#pragma unroll
    for (int kk = 0; kk < 2; kk++) {
        int c = blockIdx.x + kk * NBLK2;          // 2*391 = 782 exactly
        int nbase = c << GSHIFT;
        int beg = c * CAP;
        int cnt = gcnt[c]; if (cnt > CAP) cnt = CAP;
        int* eL = kk ? eL1 : eL0;

        __syncthreads();   // previous iteration done with hist/adl/nstart/cursor
        if (t < GNPB) {
            hist[t] = 0;
            adl[t] = (nbase + t < N_NODES) ? ad1[nbase + t] : 0.f;
        }
        __syncthreads();
        // histogram of local dst
        for (int j = t; j < cnt; j += BPG)
            atomicAdd(&hist[partP[beg + j] & (GNPB - 1)], 1);
        __syncthreads();
        if (t < GNPB) sscan[t] = hist[t];
        __syncthreads();
        for (int o = 1; o < GNPB; o <<= 1) {
            int u = (t < GNPB && t >= o) ? sscan[t - o] : 0;
            __syncthreads();
            if (t < GNPB) sscan[t] += u;
            __syncthreads();
        }
        if (t < GNPB) {
            int ex = sscan[t] - hist[t];
            nstart[t] = ex;
            cursor[t] = ex;
        }
        __syncthreads();
        // scatter src into LDS sorted by local dst
        for (int j = t; j < cnt; j += BPG) {
            int pk = partP[beg + j];
            int pos = atomicAdd(&cursor[pk & (GNPB - 1)], 1);
            eL[pos] = pk >> GSHIFT;
        }
        __syncthreads();

        // ---- phase 1 aggregation: 4-lane team per node ----
        int gnode = nbase + node;
        bool valid = gnode < N_NODES;
        int ns = nstart[node];
        int ne = ns + hist[node];    // hist==0 for OOB nodes
        ns_r[kk] = ns; ne_r[kk] = ne;
        float add = adl[node];

        float denom = 0.f;
        float acc[F_HID];
#pragma unroll
        for (int f = 0; f < F_HID; f++) acc[f] = 0.f;
        for (int i = ns + lane; i < ne; i += 4) {
            int s = eL[i];
            const float4* hp = (const float4*)(h1 + (size_t)s * F_HID);
            float4 p0 = hp[0], p1 = hp[1];
            float e = p0.x * ws0 + p0.y * ws1 + p0.z * ws2 + p0.w * ws3
                    + p1.x * ws4 + p1.y * ws5 + p1.z * ws6 + p1.w * ws7 + add;
            e = e >= 0.f ? e : NEG_SLOPE * e;
            float ee = __expf(e);
            denom += ee;
            acc[0] += ee * p0.x; acc[1] += ee * p0.y; acc[2] += ee * p0.z; acc[3] += ee * p0.w;
            acc[4] += ee * p1.x; acc[5] += ee * p1.y; acc[6] += ee * p1.z; acc[7] += ee * p1.w;
        }
#pragma unroll
        for (int o = 2; o > 0; o >>= 1) {
            denom += __shfl_xor(denom, o, 4);
#pragma unroll
            for (int f = 0; f < F_HID; f++) acc[f] += __shfl_xor(acc[f], o, 4);
        }
        if (lane == 0 && valid) {
            float inv = denom > 0.f ? 1.f / denom : 0.f;
            float o0 = 0.f, o1 = 0.f;
#pragma unroll
            for (int f = 0; f < F_HID; f++) {
                float v = acc[f] * inv + b1[f];
                v = v > 0.f ? v : 0.f;  // relu
                o0 += v * W2[f * F_OUT + 0];
                o1 += v * W2[f * F_OUT + 1];
            }
            float as2v = o0 * aw_s2[0] + o1 * aw_s2[1];
            float ad2v = o0 * aw_d2[0] + o1 * aw_d2[1];
            // device-scope atomic stores: cross-XCD-coherent P2 publication
            unsigned int* pp = (unsigned int*)&P2[gnode];
            __hip_atomic_store(pp + 0, __float_as_uint(as2v), __ATOMIC_RELAXED, __HIP_MEMORY_SCOPE_AGENT);
            __hip_atomic_store(pp + 1, __float_as_uint(o0),   __ATOMIC_RELAXED, __HIP_MEMORY_SCOPE_AGENT);
            __hip_atomic_store(pp + 2, __float_as_uint(o1),   __ATOMIC_RELAXED, __HIP_MEMORY_SCOPE_AGENT);
            __hip_atomic_store(pp + 3, __float_as_uint(ad2v), __ATOMIC_RELAXED, __HIP_MEMORY_SCOPE_AGENT);
            ad2s[kk * GNPB + node] = ad2v;
        }
    }

    // ---- all P2 globally visible before any phase-2 gather ----
    __threadfence();
    grid.sync();
    __threadfence();

    // ---- phase 2: layer-2 aggregation for the same 2x128 nodes, src lists from LDS ----
#pragma unroll
    for (int kk = 0; kk < 2; kk++) {
        int c = blockIdx.x + kk * NBLK2;
        int nbase = c << GSHIFT;
        int gnode = nbase + node;
        bool valid = gnode < N_NODES;
        const int* eL = kk ? eL1 : eL0;
        int ns = ns_r[kk], ne = ne_r[kk];
        float add2 = ad2s[kk * GNPB + node];

        float d2 = 0.f, a0 = 0.f, a1 = 0.f;
        for (int i = ns + lane; i < ne; i += 4) {
            int s = eL[i];
            float4 q = P2[s];   // (as2, h2x, h2y, ad2) - 1.6MB table
            float e = q.x + add2;
            e = e >= 0.f ? e : NEG_SLOPE * e;
            float ee = __expf(e);
            d2 += ee;
            a0 += ee * q.y;
            a1 += ee * q.z;
        }
#pragma unroll
        for (int o = 2; o > 0; o >>= 1) {
            d2 += __shfl_xor(d2, o, 4);
            a0 += __shfl_xor(a0, o, 4);
            a1 += __shfl_xor(a1, o, 4);
        }
        if (lane == 0 && valid) {
            float inv = d2 > 0.f ? 1.f / d2 : 0.f;
            float o0 = a0 * inv + b2[0];
            float o1 = a1 * inv + b2[1];
            float M = fmaxf(o0, o1);
            float l = M + logf(__expf(o0 - M) + __expf(o1 - M));
            ((float2*)out)[gnode] = make_float2(o0 - l, o1 - l);
        }
    }
}

extern "C" void kernel_launch(void* const* d_in, const int* in_sizes, int n_in,
                              void* d_out, int out_size, void* d_ws, size_t ws_size,
                              hipStream_t stream) {
    const float* x      = (const float*)d_in[0];
    const void*  eidx   = d_in[1];
    const float* W1     = (const float*)d_in[2];
    const float* a_src1 = (const float*)d_in[3];
    const float* a_dst1 = (const float*)d_in[4];
    const float* b1     = (const float*)d_in[5];
    const float* W2     = (const float*)d_in[6];
    const float* a_src2 = (const float*)d_in[7];
    const float* a_dst2 = (const float*)d_in[8];
    const float* b2     = (const float*)d_in[9];
    float* out = (float*)d_out;

    const size_t N = N_NODES;
    const size_t PADDED = (size_t)GNBUCK * CAP;   // 3,603,456

    // ---- workspace layout ----
    int* wsi = (int*)d_ws;
    float* wsf = (float*)d_ws;
    size_t o = 0;
    int* partP    = wsi + o;      o += PADDED;     // packed (src<<7)|(dst&127), padded buckets
    int* gcnt     = wsi + o;      o += 800;        // 782 bucket counts (zeroed)
    float* ad1    = wsf + o;      o += N;
    o = (o + 15) & ~(size_t)15;                    // 64B-align h1
    float* h1     = wsf + o;      o += 8 * N;
    float4* P2    = (float4*)(wsf + o); o += 4 * N; // (as2, h2x, h2y, ad2), 16B aligned

    hipMemsetAsync(gcnt, 0, 800 * sizeof(int), stream);

    part_node1_k<<<NB_PART + NB_NODE1, BP, 0, stream>>>(eidx, gcnt, partP,
                                                        x, W1, a_dst1, h1, ad1);

    void* kargs[] = {(void*)&gcnt, (void*)&partP, (void*)&a_src1, (void*)&ad1,
                     (void*)&h1, (void*)&b1, (void*)&W2, (void*)&a_src2,
                     (void*)&a_dst2, (void*)&P2, (void*)&b2, (void*)&out};
    hipLaunchCooperativeKernel(reinterpret_cast<void*>(gatF12_k),
                               dim3(NBLK2), dim3(BPG), kargs, 0, stream);
}

// Round 9
// 165.970 us; speedup vs baseline: 2.2351x; 2.2351x over previous
//
#include <hip/hip_runtime.h>
#include <hip/hip_bf16.h>

#define N_NODES 100000
#define N_EDGES 3200000
#define F_IN 36
#define F_HID 8
#define F_OUT 2
#define NEG_SLOPE 0.2f

// bucket parameters: 128 nodes per bucket, padded regions of CAP edges
#define GSHIFT 7
#define GNPB 128                     // nodes per bucket
#define GNBUCK 782                   // ceil(N_NODES / GNPB)
#define CAP 4608                     // per-bucket capacity (mean 4092, +8 sigma)
#define NB_PART 256                  // partition blocks
#define CHUNK 12500                  // N_EDGES / NB_PART exactly
#define BP 1024                      // block size (partition + node1 sections)
#define NB_NODE1 98                  // ceil(N_NODES / BP)
#define BPG 512                      // gatF1 block size (8 waves)

// ---------- inline index-dtype detection (wave 0, 2 loads/lane + ballot) ----------
// int64 input => odd 32-bit words of first 128 index pairs are all zero.
__device__ __forceinline__ int detect_is64(const void* eidx, int* s_flag) {
    if (threadIdx.x < 64) {
        const unsigned int* p = (const unsigned int*)eidx;
        unsigned int v1 = p[2 * threadIdx.x + 1];
        unsigned int v2 = p[2 * (threadIdx.x + 64) + 1];
        unsigned long long m = __ballot(v1 != 0u || v2 != 0u);
        if (threadIdx.x == 0) *s_flag = (m == 0ull) ? 1 : 0;
    }
    __syncthreads();
    return *s_flag;
}

// ---------- merged: partition (blocks 0..255) + node1 transform (blocks 256..353) ----------
// Round-9 change (single, per-dispatch-attributable): partition pass-1/pass-2
// global reads vectorized 4 elems/thread/round (int4 / longlong2). The poison
// fill flushes L3 every iteration, so these passes read ~51MB COLD at ~900cy;
// scalar loads cap lines-in-flight and made pass1 alone ~18us. gcnt stays
// DENSE (round-3's GSTRIDE padding spread the 200K reservation atomics over
// 782 lines - the suspected cause of round-3's +7us, now unbundled).
// Partition: pass 1 LDS histogram -> global range reservation -> Hillis-Steele
// scan -> pass 2 LDS counting-sort scatter -> pass 3 coalesced run writes.
__global__ void part_node1_k(const void* __restrict__ eidx, int* __restrict__ gcnt,
                             int* __restrict__ partP,
                             const float* __restrict__ x, const float* __restrict__ W1,
                             const float* __restrict__ aw_d,
                             float* __restrict__ h1, float* __restrict__ ad1) {
    if (blockIdx.x < NB_PART) {
        // ================= partition section =================
        __shared__ int sortbuf[CHUNK];    // 50000 B
        __shared__ int hist[GNBUCK];
        __shared__ int spre[GNBUCK];      // inclusive prefix of hist
        __shared__ int cursor[GNBUCK];
        __shared__ int gbase[GNBUCK];
        __shared__ int s_flag;
        int t = threadIdx.x;
        for (int i = t; i < GNBUCK; i += BP) hist[i] = 0;
        int f = detect_is64(eidx, &s_flag);   // ends with __syncthreads()
        int beg = blockIdx.x * CHUNK;
        int end = beg + CHUNK;                // exact, no partial blocks
        const int BULK = (CHUNK / (4 * BP)) * (4 * BP);   // 12288

        // ---- pass 1: histogram of dst buckets, 4 elems/thread/round ----
        if (f) {
            const long long* p64 = (const long long*)eidx;
#pragma unroll
            for (int r = 0; r < CHUNK / (4 * BP); r++) {
                int base = beg + 4 * t + r * 4 * BP;
                longlong2 d01 = *(const longlong2*)(p64 + N_EDGES + base);
                longlong2 d23 = *(const longlong2*)(p64 + N_EDGES + base + 2);
                atomicAdd(&hist[(int)d01.x >> GSHIFT], 1);
                atomicAdd(&hist[(int)d01.y >> GSHIFT], 1);
                atomicAdd(&hist[(int)d23.x >> GSHIFT], 1);
                atomicAdd(&hist[(int)d23.y >> GSHIFT], 1);
            }
            for (int i = beg + BULK + t; i < end; i += BP)
                atomicAdd(&hist[(int)p64[N_EDGES + i] >> GSHIFT], 1);
        } else {
            const int* p = (const int*)eidx;
#pragma unroll
            for (int r = 0; r < CHUNK / (4 * BP); r++) {
                int base = beg + 4 * t + r * 4 * BP;
                int4 dv = *(const int4*)(p + N_EDGES + base);
                atomicAdd(&hist[dv.x >> GSHIFT], 1);
                atomicAdd(&hist[dv.y >> GSHIFT], 1);
                atomicAdd(&hist[dv.z >> GSHIFT], 1);
                atomicAdd(&hist[dv.w >> GSHIFT], 1);
            }
            for (int i = beg + BULK + t; i < end; i += BP)
                atomicAdd(&hist[p[N_EDGES + i] >> GSHIFT], 1);
        }
        __syncthreads();
        // global reservation (DENSE gcnt) + scan init
        if (t < GNBUCK) {
            int c = hist[t];
            gbase[t] = c ? atomicAdd(&gcnt[t], c) : 0;
            spre[t] = c;
        }
        __syncthreads();
        // Hillis-Steele inclusive scan over 782 buckets (10 steps)
        for (int off = 1; off < GNBUCK; off <<= 1) {
            int v = 0;
            if (t < GNBUCK && t >= off) v = spre[t - off];
            __syncthreads();
            if (t < GNBUCK && t >= off) spre[t] += v;
            __syncthreads();
        }
        if (t < GNBUCK) cursor[t] = spre[t] - hist[t];   // exclusive offset
        __syncthreads();
        // ---- pass 2: scatter into LDS sortbuf grouped by bucket ----
        if (f) {
            const long long* p64 = (const long long*)eidx;
#pragma unroll
            for (int r = 0; r < CHUNK / (4 * BP); r++) {
                int base = beg + 4 * t + r * 4 * BP;
                longlong2 s01 = *(const longlong2*)(p64 + base);
                longlong2 s23 = *(const longlong2*)(p64 + base + 2);
                longlong2 d01 = *(const longlong2*)(p64 + N_EDGES + base);
                longlong2 d23 = *(const longlong2*)(p64 + N_EDGES + base + 2);
                int d, pos;
                d = (int)d01.x; pos = atomicAdd(&cursor[d >> GSHIFT], 1);
                sortbuf[pos] = ((int)s01.x << GSHIFT) | (d & (GNPB - 1));
                d = (int)d01.y; pos = atomicAdd(&cursor[d >> GSHIFT], 1);
                sortbuf[pos] = ((int)s01.y << GSHIFT) | (d & (GNPB - 1));
                d = (int)d23.x; pos = atomicAdd(&cursor[d >> GSHIFT], 1);
                sortbuf[pos] = ((int)s23.x << GSHIFT) | (d & (GNPB - 1));
                d = (int)d23.y; pos = atomicAdd(&cursor[d >> GSHIFT], 1);
                sortbuf[pos] = ((int)s23.y << GSHIFT) | (d & (GNPB - 1));
            }
            for (int i = beg + BULK + t; i < end; i += BP) {
                int s = (int)p64[i];
                int d = (int)p64[N_EDGES + i];
                int pos = atomicAdd(&cursor[d >> GSHIFT], 1);
                sortbuf[pos] = (s << GSHIFT) | (d & (GNPB - 1));
            }
        } else {
            const int* p = (const int*)eidx;
#pragma unroll
            for (int r = 0; r < CHUNK / (4 * BP); r++) {
                int base = beg + 4 * t + r * 4 * BP;
                int4 sv = *(const int4*)(p + base);
                int4 dv = *(const int4*)(p + N_EDGES + base);
                int pos;
                pos = atomicAdd(&cursor[dv.x >> GSHIFT], 1);
                sortbuf[pos] = (sv.x << GSHIFT) | (dv.x & (GNPB - 1));
                pos = atomicAdd(&cursor[dv.y >> GSHIFT], 1);
                sortbuf[pos] = (sv.y << GSHIFT) | (dv.y & (GNPB - 1));
                pos = atomicAdd(&cursor[dv.z >> GSHIFT], 1);
                sortbuf[pos] = (sv.z << GSHIFT) | (dv.z & (GNPB - 1));
                pos = atomicAdd(&cursor[dv.w >> GSHIFT], 1);
                sortbuf[pos] = (sv.w << GSHIFT) | (dv.w & (GNPB - 1));
            }
            for (int i = beg + BULK + t; i < end; i += BP) {
                int s = p[i];
                int d = p[N_EDGES + i];
                int pos = atomicAdd(&cursor[d >> GSHIFT], 1);
                sortbuf[pos] = (s << GSHIFT) | (d & (GNPB - 1));
            }
        }
        __syncthreads();
        // ---- pass 3: coalesced run writes; recover bucket via binary search on spre ----
        for (int i = t; i < CHUNK; i += BP) {
            int lo = 0, hi = GNBUCK - 1;
            while (lo < hi) {
                int mid = (lo + hi) >> 1;
                if (spre[mid] > i) hi = mid; else lo = mid + 1;
            }
            int b = lo;
            int gp = gbase[b] + (i - (spre[b] - hist[b]));
            if (gp < CAP) partP[b * CAP + gp] = sortbuf[i];
        }
    } else {
        // ================= node1 section: h1 = x @ W1, ad1 ==================
        int n = (blockIdx.x - NB_PART) * BP + threadIdx.x;
        if (n >= N_NODES) return;
        float acc[F_HID];
#pragma unroll
        for (int f = 0; f < F_HID; f++) acc[f] = 0.f;
        const float4* xp = (const float4*)(x + (size_t)n * F_IN);  // 36 floats = 9 float4
#pragma unroll
        for (int q = 0; q < 9; q++) {
            float4 xv = xp[q];
            const float* w = W1 + q * 4 * F_HID;
#pragma unroll
            for (int f = 0; f < F_HID; f++) {
                acc[f] += xv.x * w[0 * F_HID + f] + xv.y * w[1 * F_HID + f]
                        + xv.z * w[2 * F_HID + f] + xv.w * w[3 * F_HID + f];
            }
        }
        float d = 0.f;
#pragma unroll
        for (int f = 0; f < F_HID; f++) d += acc[f] * aw_d[f];
        float4* hp = (float4*)(h1 + (size_t)n * F_HID);
        hp[0] = make_float4(acc[0], acc[1], acc[2], acc[3]);
        hp[1] = make_float4(acc[4], acc[5], acc[6], acc[7]);
        ad1[n] = d;
    }
}

// ---------- fused layer 1: one block per bucket (128 nodes), own padded range only ----------
// LDS counting sort (int atomics), emits padded e_srcP + rowinfo, then 4-lane-team
// aggregation. Per edge: ONE random 64B-line gather (h1 row, 32B aligned); the
// src attention logit as1 = dot(h1row, a_src1) is recomputed in-register (8 FMA).
// Epilogue packs P2[node] = (as2, h2x, h2y, ad2) for gat2's single-gather loop.
__global__ void gatF1_k(const int* __restrict__ gcnt, const int* __restrict__ partP,
                        int* __restrict__ e_srcP, int2* __restrict__ rowinfo,
                        const float* __restrict__ aw_s1, const float* __restrict__ ad1,
                        const float* __restrict__ h1, const float* __restrict__ b1,
                        const float* __restrict__ W2, const float* __restrict__ aw_s2,
                        const float* __restrict__ aw_d2, float4* __restrict__ P2) {
    __shared__ int eL[CAP];
    __shared__ int hist[GNPB];
    __shared__ int nstart[GNPB];
    __shared__ int cursor[GNPB];
    __shared__ int sscan[GNPB];
    __shared__ float adl[GNPB];
    int t = threadIdx.x;
    int c = blockIdx.x;
    int nbase = c << GSHIFT;
    int beg = c * CAP;
    int cnt = gcnt[c]; if (cnt > CAP) cnt = CAP;

    if (t < GNPB) {
        hist[t] = 0;
        adl[t] = (nbase + t < N_NODES) ? ad1[nbase + t] : 0.f;
    }
    __syncthreads();
    // histogram of local dst
    for (int j = t; j < cnt; j += BPG)
        atomicAdd(&hist[partP[beg + j] & (GNPB - 1)], 1);
    __syncthreads();
    if (t < GNPB) sscan[t] = hist[t];
    __syncthreads();
    for (int o = 1; o < GNPB; o <<= 1) {
        int u = (t < GNPB && t >= o) ? sscan[t - o] : 0;
        __syncthreads();
        if (t < GNPB) sscan[t] += u;
        __syncthreads();
    }
    if (t < GNPB) {
        int ex = sscan[t] - hist[t];
        nstart[t] = ex;
        cursor[t] = ex;
        int node = nbase + t;
        if (node < N_NODES) rowinfo[node] = make_int2(beg + ex, hist[t]);
    }
    __syncthreads();
    // scatter src into LDS sorted by local dst
    for (int j = t; j < cnt; j += BPG) {
        int pk = partP[beg + j];
        int pos = atomicAdd(&cursor[pk & (GNPB - 1)], 1);
        eL[pos] = pk >> GSHIFT;
    }
    __syncthreads();
    // write sorted e_srcP for gat2 (coalesced, padded layout)
    for (int i = t; i < cnt; i += BPG) e_srcP[beg + i] = eL[i];

    // aggregate: 4-lane team per node (512/4 = 128 teams)
    int node = t >> 2;
    int lane = t & 3;
    int gnode = nbase + node;
    if (gnode >= N_NODES) return;
    int ns = nstart[node];
    int ne = ns + hist[node];
    float add = adl[node];

    // a_src1 weights in registers (broadcast, L2/L1-cached constants)
    float ws0 = aw_s1[0], ws1 = aw_s1[1], ws2 = aw_s1[2], ws3 = aw_s1[3];
    float ws4 = aw_s1[4], ws5 = aw_s1[5], ws6 = aw_s1[6], ws7 = aw_s1[7];

    float denom = 0.f;
    float acc[F_HID];
#pragma unroll
    for (int f = 0; f < F_HID; f++) acc[f] = 0.f;
    for (int i = ns + lane; i < ne; i += 4) {
        int s = eL[i];
        const float4* hp = (const float4*)(h1 + (size_t)s * F_HID);
        float4 p0 = hp[0], p1 = hp[1];
        // recompute as1[s] in-register from the row we gathered anyway
        float e = p0.x * ws0 + p0.y * ws1 + p0.z * ws2 + p0.w * ws3
                + p1.x * ws4 + p1.y * ws5 + p1.z * ws6 + p1.w * ws7 + add;
        e = e >= 0.f ? e : NEG_SLOPE * e;
        float ee = __expf(e);
        denom += ee;
        acc[0] += ee * p0.x; acc[1] += ee * p0.y; acc[2] += ee * p0.z; acc[3] += ee * p0.w;
        acc[4] += ee * p1.x; acc[5] += ee * p1.y; acc[6] += ee * p1.z; acc[7] += ee * p1.w;
    }
#pragma unroll
    for (int o = 2; o > 0; o >>= 1) {
        denom += __shfl_xor(denom, o, 4);
#pragma unroll
        for (int f = 0; f < F_HID; f++) acc[f] += __shfl_xor(acc[f], o, 4);
    }
    if (lane == 0) {
        float inv = denom > 0.f ? 1.f / denom : 0.f;
        float o0 = 0.f, o1 = 0.f;
#pragma unroll
        for (int f = 0; f < F_HID; f++) {
            float v = acc[f] * inv + b1[f];
            v = v > 0.f ? v : 0.f;  // relu
            o0 += v * W2[f * F_OUT + 0];
            o1 += v * W2[f * F_OUT + 1];
        }
        float as2v = o0 * aw_s2[0] + o1 * aw_s2[1];
        float ad2v = o0 * aw_d2[0] + o1 * aw_d2[1];
        P2[gnode] = make_float4(as2v, o0, o1, ad2v);
    }
}

// ---------- fused layer 2: 16 lanes/node, single float4 gather per edge ----------
__global__ void gat2_k(const int2* __restrict__ rowinfo, const int* __restrict__ e_srcP,
                       const float4* __restrict__ P2, const float* __restrict__ b2,
                       float* __restrict__ out, int n_nodes) {
    int gid = blockIdx.x * 16 + (threadIdx.x >> 4);
    int lane = threadIdx.x & 15;
    if (gid >= n_nodes) return;
    int2 ri = rowinfo[gid];
    float add = P2[gid].w;  // ad2 of dst node

    float denom = 0.f, a0 = 0.f, a1 = 0.f;
    int jend = ri.x + ri.y;
    for (int j = ri.x + lane; j < jend; j += 16) {
        int s = e_srcP[j];
        float4 q = P2[s];   // (as2, h2x, h2y, ad2)
        float e = q.x + add;
        e = e >= 0.f ? e : NEG_SLOPE * e;
        float ee = __expf(e);
        denom += ee;
        a0 += ee * q.y;
        a1 += ee * q.z;
    }
#pragma unroll
    for (int o = 8; o > 0; o >>= 1) {
        denom += __shfl_xor(denom, o, 16);
        a0 += __shfl_xor(a0, o, 16);
        a1 += __shfl_xor(a1, o, 16);
    }

    if (lane == 0) {
        float inv = denom > 0.f ? 1.f / denom : 0.f;
        float o0 = a0 * inv + b2[0];
        float o1 = a1 * inv + b2[1];
        float M = fmaxf(o0, o1);
        float l = M + logf(__expf(o0 - M) + __expf(o1 - M));
        ((float2*)out)[gid] = make_float2(o0 - l, o1 - l);
    }
}

extern "C" void kernel_launch(void* const* d_in, const int* in_sizes, int n_in,
                              void* d_out, int out_size, void* d_ws, size_t ws_size,
                              hipStream_t stream) {
    const float* x      = (const float*)d_in[0];
    const void*  eidx   = d_in[1];
    const float* W1     = (const float*)d_in[2];
    const float* a_src1 = (const float*)d_in[3];
    const float* a_dst1 = (const float*)d_in[4];
    const float* b1     = (const float*)d_in[5];
    const float* W2     = (const float*)d_in[6];
    const float* a_src2 = (const float*)d_in[7];
    const float* a_dst2 = (const float*)d_in[8];
    const float* b2     = (const float*)d_in[9];
    float* out = (float*)d_out;

    const size_t N = N_NODES;
    const size_t PADDED = (size_t)GNBUCK * CAP;   // 3,603,456

    // ---- workspace layout (4B words; h1 kept 64B-aligned so 32B rows never straddle a line) ----
    int* wsi = (int*)d_ws;
    float* wsf = (float*)d_ws;
    size_t o = 0;
    int* partP    = wsi + o;      o += PADDED;     // packed (src<<7)|(dst&127), padded buckets
    int* e_srcP   = wsi + o;      o += PADDED;     // dst-sorted src, padded buckets
    int* gcnt     = wsi + o;      o += 800;        // 782 bucket counts (zeroed, dense)
    int2* rowinfo = (int2*)(wsi + o); o += 2 * N;  // (start, len) per node, 8B aligned
    float* ad1    = wsf + o;      o += N;
    o = (o + 15) & ~(size_t)15;                    // 64B-align h1
    float* h1     = wsf + o;      o += 8 * N;
    float4* P2    = (float4*)(wsf + o); o += 4 * N; // (as2, h2x, h2y, ad2), 16B aligned

    const int gridG = (int)(N / 16);            // 6250

    hipMemsetAsync(gcnt, 0, 800 * sizeof(int), stream);

    part_node1_k<<<NB_PART + NB_NODE1, BP, 0, stream>>>(eidx, gcnt, partP,
                                                        x, W1, a_dst1, h1, ad1);
    gatF1_k<<<GNBUCK, BPG, 0, stream>>>(gcnt, partP, e_srcP, rowinfo, a_src1, ad1, h1, b1,
                                        W2, a_src2, a_dst2, P2);
    gat2_k<<<gridG, 256, 0, stream>>>(rowinfo, e_srcP, P2, b2, out, (int)N);
}